// Round 6
// baseline (306.493 us; speedup 1.0000x reference)
//
#include <hip/hip_runtime.h>
#include <math.h>
#include <stdint.h>

#define NB   4
#define NC   1025
#define WSZ  2048
#define STEP 1024
#define FRM  256
#define BAT  32
#define TT   262144
#define KC   128     // bin chunk held in LDS by the synth kernel

// 1/2048 (exact): phases are integers mod 2048 -> revolutions for v_sin/v_cos
#define RREV (1.0f / 2048.0f)

typedef float f2 __attribute__((ext_vector_type(2)));

__device__ __forceinline__ float tanh_fast(float z) {
    float e = __expf(2.0f * z);
    return 1.0f - 2.0f / (e + 1.0f);   // exact tanh identity; inf/0 saturate to +/-1
}

// hardware cis: idx taken mod 2048, argument in revolutions (exact, no range reduction)
__device__ __forceinline__ void cis_rev(int idx, float* c, float* s) {
    float rev = (float)(idx & 2047) * RREV;
    *c = __builtin_amdgcn_cosf(rev);
    *s = __builtin_amdgcn_sinf(rev);
}

// ---------------- setup: compact nonzero bins per block + softmax(mixer) + hann table ----------------
__global__ __launch_bounds__(1024) void setup_kernel(
    const float* __restrict__ transfers, const float* __restrict__ mixer,
    int* __restrict__ counts, int* __restrict__ bins, float* __restrict__ tvals,
    float* __restrict__ wmix, float* __restrict__ hann, int kmax)
{
    int i = blockIdx.x, tid = threadIdx.x;
    __shared__ int wcnt[16], woff[16];
    if (i == 0) {                                   // hann[n] = 0.5 - 0.5 cos(2pi n/2048)
        float cc, ss; cis_rev(tid, &cc, &ss);
        hann[tid] = 0.5f - 0.5f * cc;
    }
    float tv = transfers[i * NC + tid];
    bool nz = (tv != 0.0f);
    unsigned long long mask = __ballot(nz);
    int lane = tid & 63, w = tid >> 6;
    int within = __popcll(mask & ((1ULL << lane) - 1ULL));
    if (lane == 0) wcnt[w] = __popcll(mask);
    __syncthreads();
    if (tid == 0) {
        int acc = 0;
        for (int q = 0; q < 16; ++q) { woff[q] = acc; acc += wcnt[q]; }
        float tvL = transfers[i * NC + 1024];       // tail bin k=1024
        if (tvL != 0.0f && acc < kmax) { bins[i * NC + acc] = 1024; tvals[i * NC + acc] = tvL; acc++; }
        counts[i] = (acc < kmax) ? acc : kmax;
        if (i == 0) {                               // softmax of mixer[5]
            float m = mixer[0];
            for (int q = 1; q < 5; ++q) m = fmaxf(m, mixer[q]);
            float e[5], s = 0.f;
            for (int q = 0; q < 5; ++q) { e[q] = __expf(mixer[q] - m); s += e[q]; }
            for (int q = 0; q < 5; ++q) wmix[q] = e[q] / s;
        }
    }
    __syncthreads();
    if (nz) {
        int pos = woff[w] + within;
        if (pos < kmax) { bins[i * NC + pos] = tid; tvals[i * NC + pos] = tv; }
    }
}

// ---------------- twiddle tables: T[i][j][n] = cis(2pi k_j n / 2048), n in [0,1024) ----------------
__global__ __launch_bounds__(256) void twiddle_kernel(
    const int* __restrict__ counts, const int* __restrict__ bins,
    float2* __restrict__ TW, int kmax)
{
    int i = blockIdx.x >> 5, c = blockIdx.x & 31;
    int K = counts[i];
    for (int j = c; j < K; j += 32) {
        int k = bins[i * NC + j];
        float2* row = TW + ((size_t)i * kmax + j) * 1024;
        for (int n = threadIdx.x; n < 1024; n += 256) {
            float cc, ss; cis_rev(k * n, &cc, &ss);
            row[n] = make_float2(cc, ss);
        }
    }
}

// shared half-frame DFT: xr[16] per lane (n = lane + 64*i), bins j = w, w+4, ... < K,
// twiddles from TW row (TWrow[lane] = cis(+k lane), conj used). Two bins per iteration
// packed into <2 x float> lanes (v_pk_fma_f32 path).
__device__ __forceinline__ void half_dft(
    const float xr[16], int K, const float2* __restrict__ TWb,
    float2* __restrict__ Hout, int lane, int w)
{
    for (int j = w; j < K; j += 8) {
        int j2 = j + 4;
        bool two = (j2 < K);
        const float2* rowA = TWb + ((size_t)j << 10);
        const float2* rowB = two ? (TWb + ((size_t)j2 << 10)) : rowA;
        float2 wA64 = rowA[64], wB64 = rowB[64];
        float2 wAl = rowA[lane], wBl = rowB[lane];
        f2 Wr, Wi, nWi;
        Wr.x = wA64.x; Wr.y = wB64.x;
        Wi.x = -wA64.y; Wi.y = -wB64.y;          // W = conj(cis(k*64))
        nWi = -Wi;
        f2 hr = 0.f, hi = 0.f;                   // packed Horner: lane0=binA, lane1=binB
#pragma unroll
        for (int i = 15; i >= 0; --i) {
            f2 xx; xx.x = xr[i]; xx.y = xr[i];
            f2 tmp = nWi * hi + xx;              // pk_fma
            f2 nr = Wr * hr + tmp;               // pk_fma
            hi = Wi * hr + Wr * hi;              // pk_mul + pk_fma
            hr = nr;
        }
        // multiply by conj(cis(k*lane)): re = hr*c + hi*s; im = hi*c - hr*s
        f2 wlc, wls;
        wlc.x = wAl.x; wlc.y = wBl.x;
        wls.x = wAl.y; wls.y = wBl.y;
        f2 re = hr * wlc + hi * wls;
        f2 im = hi * wlc - hr * wls;
        float reA = re.x, imA = im.x, reB = re.y, imB = im.y;
#pragma unroll
        for (int m = 32; m >= 1; m >>= 1) {
            reA += __shfl_xor(reA, m, 64);
            imA += __shfl_xor(imA, m, 64);
            reB += __shfl_xor(reB, m, 64);
            imB += __shfl_xor(imB, m, 64);
        }
        if (lane == 0) {
            Hout[j] = make_float2(reA, imA);
            if (two) Hout[j2] = make_float2(reB, imB);
        }
    }
}

// ---------------- analysis (block 0 only): sparse DFT of each 1024-sample half-frame ----------------
__global__ __launch_bounds__(256, 8) void analysis_kernel(
    const float* __restrict__ x, const int* __restrict__ counts,
    const float2* __restrict__ TW, float2* __restrict__ H, int iblk, int kmax)
{
    int wg = blockIdx.x;
    int b = wg >> 8, h = wg & 255;
    int tid = threadIdx.x;
    int lane = tid & 63, w = tid >> 6;
    int K = counts[iblk];
    const float* xb = x + (size_t)b * TT + (size_t)h * STEP;
    float xr[16];
#pragma unroll
    for (int i = 0; i < 16; ++i) xr[i] = xb[lane + (i << 6)];
    const float2* TWb = TW + (size_t)iblk * kmax * 1024;
    float2* Hout = H + (size_t)(b * FRM + h) * K;
    half_dft(xr, K, TWb, Hout, lane, w);
}

// ---------------- scan: S_f = H_f + (-1)^k H_{f+1};  O_f = (S_f + O_{f-1}) * t ----------------
// Kogge-Stone over 256 frames; grid = BAT*16 wgs, wg (b, j0) loops bins j = j0, j0+16, ...
__global__ __launch_bounds__(256) void scan_kernel(
    float2* __restrict__ S, const int* __restrict__ counts,
    const int* __restrict__ bins, const float* __restrict__ tvals, int iblk)
{
    int K = counts[iblk];
    int wg = blockIdx.x;
    int b = wg & (BAT - 1), j0 = wg >> 5;
    int f = threadIdx.x;
    __shared__ f2 sha[FRM];
    __shared__ float shg[FRM];
    for (int j = j0; j < K; j += 16) {
        float t = tvals[iblk * NC + j];
        int k = bins[iblk * NC + j];
        float2* Sb = S + (size_t)b * FRM * K + j;
        float2 h1 = Sb[(size_t)f * K];
        float2 h2 = (f < FRM - 1) ? Sb[(size_t)(f + 1) * K] : make_float2(0.f, 0.f);
        float sgn = (k & 1) ? -t : t;
        f2 a;
        a.x = fmaf(sgn, h2.x, h1.x * t);
        a.y = fmaf(sgn, h2.y, h1.y * t);
        float g = t;
#pragma unroll
        for (int d = 1; d < FRM; d <<= 1) {
            sha[f] = a; shg[f] = g;
            __syncthreads();
            if (f >= d) {
                f2 gg; gg.x = g; gg.y = g;
                a = gg * sha[f - d] + a;         // pk_fma
                g *= shg[f - d];
            }
            __syncthreads();
        }
        Sb[(size_t)f * K] = make_float2(a.x, a.y);
        __syncthreads();
    }
}

// ---------------- fused synthesis + next-block analysis ----------------
// grid = BAT*FRM workgroups of 256; wg (b,seg) produces samples [seg*1024,(seg+1)*1024).
// out[n1] = A + hann[n1]*B, A = sum Re[c2' e^{i2pik n1/2048}], B = sum Re[(c1-c2') e],
// c1 = g*O_{f1}, c2' = g*(-1)^k*O_{f2}; e from the L2-resident table. (A,B) are packed
// into <2 x float> accumulators -> v_pk_fma_f32. cdat stores (c2r, dr, -c2i, -di).
// The 1024 produced samples (= half-frame seg of y) are staged through LDS and the next
// block's half-frame DFT is computed in the same workgroup (y never touches HBM).
__global__ __launch_bounds__(256, 8) void fused_synth_kernel(
    const float2* __restrict__ S, float2* __restrict__ H2,
    const float2* __restrict__ TW,
    const int* __restrict__ counts, const int* __restrict__ bins,
    const float* __restrict__ gains, const float* __restrict__ wmix,
    const float* __restrict__ hann, const float* __restrict__ x,
    float* __restrict__ dout, int iblk, int do_an, int kmax)
{
    __shared__ float4 cdat[KC];     // c2r, c1r-c2r, -c2i, -(c1i-c2i)
    __shared__ float4 ystage4[256];

    int wg = blockIdx.x;
    int b = wg >> 8, seg = wg & 255;
    int tid = threadIdx.x;
    int n1 = tid << 2;
    size_t base = (size_t)b * TT + (size_t)seg * STEP + (size_t)n1;

    // early prefetch: RMW operand + hann weights (consumed only in the epilogue)
    const float* prevsrc = (iblk == 0) ? x : dout;
    float4 pv = *(const float4*)(prevsrc + base);
    float4 hv = *(const float4*)(hann + n1);
    float wsel = (iblk == 0) ? wmix[0] : 1.0f;
    float wn = wmix[iblk + 1];
    float gain = gains[iblk];

    int K = counts[iblk];
    const int* bl = bins + iblk * NC;
    const float2* Ob = S + (size_t)b * FRM * K;
    const float2* TWb = TW + (size_t)iblk * kmax * 1024;
    int f1 = seg, f2i = seg - 1;

    f2 acc0 = 0.f, acc1 = 0.f, acc2 = 0.f, acc3 = 0.f;   // (A, B) packed

    for (int c0 = 0; c0 < K; c0 += KC) {
        int cs = (K - c0 < KC) ? (K - c0) : KC;
        if (tid < cs) {
            int j = c0 + tid;
            int k = bl[j];
            float g = ((k == 0) || (k == 1024)) ? (1.0f / 2048.0f) : (2.0f / 2048.0f);
            float2 o1 = Ob[(size_t)f1 * K + j];
            float c1r = o1.x * g, c1i = o1.y * g;
            float c2r = 0.f, c2i = 0.f;
            if (f2i >= 0) {
                float2 o2 = Ob[(size_t)f2i * K + j];
                float s = (k & 1) ? -g : g;            // fold (-1)^k into second half
                c2r = o2.x * s; c2i = o2.y * s;
            }
            cdat[tid] = make_float4(c2r, c1r - c2r, -c2i, -(c1i - c2i));
        }
        __syncthreads();
        // rows are 512 float4 apart; pointer-increment addressing, x2 unroll for load pipelining
        const float4* tp = (const float4*)TWb + (((size_t)c0) << 9) + (tid << 1);
        int jj = 0;
        for (; jj + 2 <= cs; jj += 2) {
            float4 tA0 = tp[0];
            float4 tB0 = tp[1];
            float4 tA1 = tp[512];
            float4 tB1 = tp[513];
            tp += 1024;
            float4 cd0 = cdat[jj];
            float4 cd1 = cdat[jj + 1];
            f2 u0; u0.x = cd0.x; u0.y = cd0.y;   // (c2r, dr)
            f2 v0; v0.x = cd0.z; v0.y = cd0.w;   // (-c2i, -di)
            f2 u1; u1.x = cd1.x; u1.y = cd1.y;
            f2 v1; v1.x = cd1.z; v1.y = cd1.w;
            acc0 = u0 * tA0.x + acc0; acc0 = v0 * tA0.y + acc0;
            acc1 = u0 * tA0.z + acc1; acc1 = v0 * tA0.w + acc1;
            acc2 = u0 * tB0.x + acc2; acc2 = v0 * tB0.y + acc2;
            acc3 = u0 * tB0.z + acc3; acc3 = v0 * tB0.w + acc3;
            acc0 = u1 * tA1.x + acc0; acc0 = v1 * tA1.y + acc0;
            acc1 = u1 * tA1.z + acc1; acc1 = v1 * tA1.w + acc1;
            acc2 = u1 * tB1.x + acc2; acc2 = v1 * tB1.y + acc2;
            acc3 = u1 * tB1.z + acc3; acc3 = v1 * tB1.w + acc3;
        }
        if (jj < cs) {
            float4 tA = tp[0];
            float4 tB = tp[1];
            float4 cd = cdat[jj];
            f2 u; u.x = cd.x; u.y = cd.y;
            f2 v; v.x = cd.z; v.y = cd.w;
            acc0 = u * tA.x + acc0; acc0 = v * tA.y + acc0;
            acc1 = u * tA.z + acc1; acc1 = v * tA.w + acc1;
            acc2 = u * tB.x + acc2; acc2 = v * tB.y + acc2;
            acc3 = u * tB.z + acc3; acc3 = v * tB.w + acc3;
        }
        __syncthreads();
    }

    float4 yv;
    yv.x = tanh_fast(fmaf(hv.x, acc0.y, acc0.x) * gain);
    yv.y = tanh_fast(fmaf(hv.y, acc1.y, acc1.x) * gain);
    yv.z = tanh_fast(fmaf(hv.z, acc2.y, acc2.x) * gain);
    yv.w = tanh_fast(fmaf(hv.w, acc3.y, acc3.x) * gain);

    float4 dv;
    dv.x = fmaf(wsel, pv.x, wn * yv.x);
    dv.y = fmaf(wsel, pv.y, wn * yv.y);
    dv.z = fmaf(wsel, pv.z, wn * yv.z);
    dv.w = fmaf(wsel, pv.w, wn * yv.w);
    *(float4*)(dout + base) = dv;

    if (do_an) {
        ystage4[tid] = yv;
        __syncthreads();
        int K2 = counts[iblk + 1];
        if (K2 > 0) {
            const float* ys = (const float*)ystage4;
            int lane = tid & 63, w = tid >> 6;
            float xr[16];
#pragma unroll
            for (int i = 0; i < 16; ++i) xr[i] = ys[lane + (i << 6)];
            const float2* TW2b = TW + (size_t)(iblk + 1) * kmax * 1024;
            float2* Hout = H2 + (size_t)(b * FRM + seg) * K2;
            half_dft(xr, K2, TW2b, Hout, lane, w);
        }
    }
}

extern "C" void kernel_launch(void* const* d_in, const int* in_sizes, int n_in,
                              void* d_out, int out_size, void* d_ws, size_t ws_size,
                              hipStream_t stream)
{
    const float* x         = (const float*)d_in[0];
    const float* transfers = (const float*)d_in[1];
    const float* gains     = (const float*)d_in[2];
    const float* mixer     = (const float*)d_in[3];
    float* dout = (float*)d_out;

    uint8_t* ws = (uint8_t*)d_ws;
    int*   counts = (int*)ws;                          // 16 B
    int*   bins   = (int*)(ws + 64);                   // 4*1025*4 = 16400 B
    float* tvals  = (float*)(ws + 64 + 16400);         // 16400 B
    float* wmix   = (float*)(ws + 64 + 16400 + 16400); // 20 B
    float* hann   = (float*)(ws + 36864);              // 1024 floats
    const size_t HDR = 65536;

    // per-k bytes: two ping-pong S buffers (2 * BAT*FRM*8) + NB twiddle rows (NB*1024*8)
    long long perk = 2LL * BAT * FRM * 8 + (long long)NB * 1024 * 8;
    long long km = ((long long)ws_size - (long long)HDR) / perk;
    int kmax = (int)((km < 1) ? 1 : ((km > NC) ? NC : km));
    float2* S0 = (float2*)(ws + HDR);
    float2* S1 = S0 + (size_t)BAT * FRM * kmax;
    float2* TW = S1 + (size_t)BAT * FRM * kmax;        // NB * kmax * 1024 float2

    setup_kernel<<<NB, 1024, 0, stream>>>(transfers, mixer, counts, bins, tvals, wmix, hann, kmax);
    twiddle_kernel<<<NB * 32, 256, 0, stream>>>(counts, bins, TW, kmax);
    analysis_kernel<<<BAT * FRM, 256, 0, stream>>>(x, counts, TW, S0, 0, kmax);

    float2* cur = S0;
    float2* nxt = S1;
    for (int i = 0; i < NB; ++i) {
        scan_kernel<<<BAT * 32, 256, 0, stream>>>(cur, counts, bins, tvals, i);
        fused_synth_kernel<<<BAT * FRM, 256, 0, stream>>>(cur, nxt, TW, counts, bins, gains,
                                                          wmix, hann, x, dout, i,
                                                          (i < NB - 1) ? 1 : 0, kmax);
        float2* t = cur; cur = nxt; nxt = t;
    }
}

// Round 7
// 294.397 us; speedup vs baseline: 1.0411x; 1.0411x over previous
//
#include <hip/hip_runtime.h>
#include <math.h>
#include <stdint.h>

#define NB   4
#define NC   1025
#define WSZ  2048
#define STEP 1024
#define FRM  256
#define BAT  32
#define TT   262144
#define KC   64      // bin chunk staged in LDS by the synth kernel

// 1/2048 (exact): phases are integers mod 2048 -> revolutions for v_sin/v_cos
#define RREV (1.0f / 2048.0f)

typedef float f2 __attribute__((ext_vector_type(2)));

__device__ __forceinline__ float tanh_fast(float z) {
    float e = __expf(2.0f * z);
    return 1.0f - 2.0f / (e + 1.0f);   // exact tanh identity; inf/0 saturate to +/-1
}

// hardware cis: idx taken mod 2048, argument in revolutions (exact, no range reduction)
__device__ __forceinline__ void cis_rev(int idx, float* c, float* s) {
    float rev = (float)(idx & 2047) * RREV;
    *c = __builtin_amdgcn_cosf(rev);
    *s = __builtin_amdgcn_sinf(rev);
}

// ---------------- setup: compact nonzero bins per block + softmax(mixer) + hann table ----------------
__global__ __launch_bounds__(1024) void setup_kernel(
    const float* __restrict__ transfers, const float* __restrict__ mixer,
    int* __restrict__ counts, int* __restrict__ bins, float* __restrict__ tvals,
    float* __restrict__ wmix, float* __restrict__ hann, int kmax)
{
    int i = blockIdx.x, tid = threadIdx.x;
    __shared__ int wcnt[16], woff[16];
    if (i == 0) {                                   // hann[n] = 0.5 - 0.5 cos(2pi n/2048)
        float cc, ss; cis_rev(tid, &cc, &ss);
        hann[tid] = 0.5f - 0.5f * cc;
    }
    float tv = transfers[i * NC + tid];
    bool nz = (tv != 0.0f);
    unsigned long long mask = __ballot(nz);
    int lane = tid & 63, w = tid >> 6;
    int within = __popcll(mask & ((1ULL << lane) - 1ULL));
    if (lane == 0) wcnt[w] = __popcll(mask);
    __syncthreads();
    if (tid == 0) {
        int acc = 0;
        for (int q = 0; q < 16; ++q) { woff[q] = acc; acc += wcnt[q]; }
        float tvL = transfers[i * NC + 1024];       // tail bin k=1024
        if (tvL != 0.0f && acc < kmax) { bins[i * NC + acc] = 1024; tvals[i * NC + acc] = tvL; acc++; }
        counts[i] = (acc < kmax) ? acc : kmax;
        if (i == 0) {                               // softmax of mixer[5]
            float m = mixer[0];
            for (int q = 1; q < 5; ++q) m = fmaxf(m, mixer[q]);
            float e[5], s = 0.f;
            for (int q = 0; q < 5; ++q) { e[q] = __expf(mixer[q] - m); s += e[q]; }
            for (int q = 0; q < 5; ++q) wmix[q] = e[q] / s;
        }
    }
    __syncthreads();
    if (nz) {
        int pos = woff[w] + within;
        if (pos < kmax) { bins[i * NC + pos] = tid; tvals[i * NC + pos] = tv; }
    }
}

// ---------------- factored twiddle tables (tiny, L1-resident) ----------------
// cisA[i][j][m] = cis(2pi k_j m /2048), m in [0,64);  cisB[i][j][q] = cis(2pi k_j 64 q/2048), q in [0,16)
__global__ __launch_bounds__(256) void table_kernel(
    const int* __restrict__ counts, const int* __restrict__ bins,
    float2* __restrict__ cisA, float2* __restrict__ cisB, int kmax)
{
    int i = blockIdx.x >> 2, c = blockIdx.x & 3;
    int K = counts[i];
    int tid = threadIdx.x;
    for (int j = c; j < K; j += 4) {
        int k = bins[i * NC + j];
        if (tid < 64) {
            float cc, ss; cis_rev(k * tid, &cc, &ss);
            cisA[((size_t)i * kmax + j) * 64 + tid] = make_float2(cc, ss);
        } else if (tid < 80) {
            int q = tid - 64;
            float cc, ss; cis_rev(k * 64 * q, &cc, &ss);
            cisB[((size_t)i * kmax + j) * 16 + q] = make_float2(cc, ss);
        }
    }
}

// shared half-frame DFT: xr[16] per lane (n = lane + 64*i), bins j = w, w+4, ... < K,
// W = conj(cisB[j][1]) = cis(-64k); final rotate by conj(cisA[j][lane]). 2-bin f2 packing.
__device__ __forceinline__ void half_dft(
    const float xr[16], int K, const float2* __restrict__ cA,
    const float2* __restrict__ cB, float2* __restrict__ Hout, int lane, int w)
{
    for (int j = w; j < K; j += 8) {
        int j2 = j + 4;
        bool two = (j2 < K);
        float2 bA = cB[(size_t)j * 16 + 1];
        float2 bB = two ? cB[(size_t)j2 * 16 + 1] : bA;
        float2 wAl = cA[(size_t)j * 64 + lane];
        float2 wBl = two ? cA[(size_t)j2 * 64 + lane] : wAl;
        f2 Wr, Wi, nWi;
        Wr.x = bA.x; Wr.y = bB.x;
        Wi.x = -bA.y; Wi.y = -bB.y;              // W = conj(cis(64k))
        nWi = -Wi;
        f2 hr = 0.f, hi = 0.f;                   // packed Horner: lane0=binA, lane1=binB
#pragma unroll
        for (int i = 15; i >= 0; --i) {
            f2 xx; xx.x = xr[i]; xx.y = xr[i];
            f2 tmp = nWi * hi + xx;              // pk_fma
            f2 nr = Wr * hr + tmp;               // pk_fma
            hi = Wi * hr + Wr * hi;
            hr = nr;
        }
        // multiply by conj(cis(k*lane)): re = hr*c + hi*s; im = hi*c - hr*s
        f2 wlc, wls;
        wlc.x = wAl.x; wlc.y = wBl.x;
        wls.x = wAl.y; wls.y = wBl.y;
        f2 re = hr * wlc + hi * wls;
        f2 im = hi * wlc - hr * wls;
        float reA = re.x, imA = im.x, reB = re.y, imB = im.y;
#pragma unroll
        for (int m = 32; m >= 1; m >>= 1) {
            reA += __shfl_xor(reA, m, 64);
            imA += __shfl_xor(imA, m, 64);
            reB += __shfl_xor(reB, m, 64);
            imB += __shfl_xor(imB, m, 64);
        }
        if (lane == 0) {
            Hout[j] = make_float2(reA, imA);
            if (two) Hout[j2] = make_float2(reB, imB);
        }
    }
}

// ---------------- analysis (block 0 only): sparse DFT of each 1024-sample half-frame ----------------
__global__ __launch_bounds__(256, 8) void analysis_kernel(
    const float* __restrict__ x, const int* __restrict__ counts,
    const float2* __restrict__ cisA, const float2* __restrict__ cisB,
    float2* __restrict__ H, int iblk, int kmax)
{
    int wg = blockIdx.x;
    int b = wg >> 8, h = wg & 255;
    int tid = threadIdx.x;
    int lane = tid & 63, w = tid >> 6;
    int K = counts[iblk];
    const float* xb = x + (size_t)b * TT + (size_t)h * STEP;
    float xr[16];
#pragma unroll
    for (int i = 0; i < 16; ++i) xr[i] = xb[lane + (i << 6)];
    const float2* cA = cisA + (size_t)iblk * kmax * 64;
    const float2* cB = cisB + (size_t)iblk * kmax * 16;
    float2* Hout = H + (size_t)(b * FRM + h) * K;
    half_dft(xr, K, cA, cB, Hout, lane, w);
}

// ---------------- scan: S_f = H_f + (-1)^k H_{f+1};  O_f = (S_f + O_{f-1}) * t ----------------
// Kogge-Stone over 256 frames; grid = BAT*32 wgs, wg (b, j0) loops bins j = j0, j0+32, ...
__global__ __launch_bounds__(256) void scan_kernel(
    float2* __restrict__ S, const int* __restrict__ counts,
    const int* __restrict__ bins, const float* __restrict__ tvals, int iblk)
{
    int K = counts[iblk];
    int wg = blockIdx.x;
    int b = wg & (BAT - 1), j0 = wg >> 5;
    int f = threadIdx.x;
    __shared__ f2 sha[FRM];
    __shared__ float shg[FRM];
    for (int j = j0; j < K; j += 32) {
        float t = tvals[iblk * NC + j];
        int k = bins[iblk * NC + j];
        float2* Sb = S + (size_t)b * FRM * K + j;
        float2 h1 = Sb[(size_t)f * K];
        float2 h2 = (f < FRM - 1) ? Sb[(size_t)(f + 1) * K] : make_float2(0.f, 0.f);
        float sgn = (k & 1) ? -t : t;
        f2 a;
        a.x = fmaf(sgn, h2.x, h1.x * t);
        a.y = fmaf(sgn, h2.y, h1.y * t);
        float g = t;
#pragma unroll
        for (int d = 1; d < FRM; d <<= 1) {
            sha[f] = a; shg[f] = g;
            __syncthreads();
            if (f >= d) {
                f2 gg; gg.x = g; gg.y = g;
                a = gg * sha[f - d] + a;         // pk_fma
                g *= shg[f - d];
            }
            __syncthreads();
        }
        Sb[(size_t)f * K] = make_float2(a.x, a.y);
        __syncthreads();
    }
}

// coefficient rotate by cisB(k q) + 4-sample accumulate: acc_i += u'*cA_i.c + v'*cA_i.s
__device__ __forceinline__ void accum_seg(
    f2& q0, f2& q1, f2& q2, f2& q3,
    float4 cd, float2 bq, float4 a0, float4 a1)
{
    f2 u; u.x = cd.x; u.y = cd.y;        // ( c2r,  c1r-c2r)
    f2 v; v.x = cd.z; v.y = cd.w;        // (-c2i, -(c1i-c2i))
    f2 up = u * bq.x + v * bq.y;
    f2 vp = v * bq.x - u * bq.y;
    q0 = up * a0.x + q0; q0 = vp * a0.y + q0;
    q1 = up * a0.z + q1; q1 = vp * a0.w + q1;
    q2 = up * a1.x + q2; q2 = vp * a1.y + q2;
    q3 = up * a1.z + q3; q3 = vp * a1.w + q3;
}

// ---------------- fused synthesis (2 segments/wg) + next-block analysis ----------------
// grid = BAT*128 wgs of 256; wg (b, s0) produces samples of segments s0 and s0+1.
// Phase factorization: n1 = 64q + m (q = tid>>4, m = (tid&15)*4); cis(k n1) =
// cis(k m) * cis(64 k q); the q-rotation folds into the coef (once per bin), the
// inner loop reads only cisA[k][m..m+3] -- a [K][64] table resident in L1.
// Both segments' outputs are staged through LDS and the next block's half-frame
// DFTs run in the same workgroup (y never touches HBM).
__global__ __launch_bounds__(256, 8) void fused_synth_kernel(
    const float2* __restrict__ S, float2* __restrict__ H2,
    const float2* __restrict__ cisA, const float2* __restrict__ cisB,
    const int* __restrict__ counts, const int* __restrict__ bins,
    const float* __restrict__ gains, const float* __restrict__ wmix,
    const float* __restrict__ hann, const float* __restrict__ x,
    float* __restrict__ dout, int iblk, int do_an, int kmax)
{
    __shared__ float4 cdat[KC][2];
    __shared__ float4 ystage4[512];

    int wg = blockIdx.x;
    int b = wg >> 7, s0 = (wg & 127) << 1;
    int tid = threadIdx.x;
    int n1 = tid << 2;
    int q = tid >> 4;
    int m = (tid & 15) << 2;

    int K = counts[iblk];
    const int* bl = bins + iblk * NC;
    const float2* Ob = S + (size_t)b * FRM * K;
    const float2* cA0 = cisA + (size_t)iblk * kmax * 64;
    const float2* cB0 = cisB + (size_t)iblk * kmax * 16;

    f2 p0 = 0.f, p1 = 0.f, p2 = 0.f, p3 = 0.f;   // seg s0   (A,B) packed
    f2 r0 = 0.f, r1 = 0.f, r2 = 0.f, r3 = 0.f;   // seg s0+1

    for (int c0 = 0; c0 < K; c0 += KC) {
        int cs = (K - c0 < KC) ? (K - c0) : KC;
        if (tid < cs) {
            int j = c0 + tid;
            int k = bl[j];
            float g = ((k == 0) || (k == 1024)) ? (1.0f / 2048.0f) : (2.0f / 2048.0f);
            float sg = (k & 1) ? -g : g;              // fold (-1)^k into second-half coef
            float2 o0 = Ob[(size_t)s0 * K + j];
            float2 o1 = Ob[(size_t)(s0 + 1) * K + j];
            float2 om = (s0 > 0) ? Ob[(size_t)(s0 - 1) * K + j] : make_float2(0.f, 0.f);
            float c2r = om.x * sg, c2i = om.y * sg;   // seg s0: c2 from frame s0-1, c1 from s0
            cdat[tid][0] = make_float4(c2r, o0.x * g - c2r, -c2i, -(o0.y * g - c2i));
            c2r = o0.x * sg; c2i = o0.y * sg;         // seg s0+1: c2 from s0, c1 from s0+1
            cdat[tid][1] = make_float4(c2r, o1.x * g - c2r, -c2i, -(o1.y * g - c2i));
        }
        __syncthreads();
        const float2* cAj = cA0 + ((size_t)c0 << 6) + m;
        const float2* cBj = cB0 + ((size_t)c0 << 4) + q;
        int jj = 0;
        for (; jj + 2 <= cs; jj += 2) {
            float4 a00 = *(const float4*)(cAj);
            float4 a01 = *(const float4*)(cAj + 2);
            float4 a10 = *(const float4*)(cAj + 64);
            float4 a11 = *(const float4*)(cAj + 66);
            float2 b0 = *cBj;
            float2 b1 = *(cBj + 16);
            cAj += 128; cBj += 32;
            float4 cd00 = cdat[jj][0],     cd01 = cdat[jj][1];
            float4 cd10 = cdat[jj + 1][0], cd11 = cdat[jj + 1][1];
            accum_seg(p0, p1, p2, p3, cd00, b0, a00, a01);
            accum_seg(r0, r1, r2, r3, cd01, b0, a00, a01);
            accum_seg(p0, p1, p2, p3, cd10, b1, a10, a11);
            accum_seg(r0, r1, r2, r3, cd11, b1, a10, a11);
        }
        if (jj < cs) {
            float4 a0 = *(const float4*)(cAj);
            float4 a1 = *(const float4*)(cAj + 2);
            float2 b0 = *cBj;
            float4 cd0 = cdat[jj][0], cd1 = cdat[jj][1];
            accum_seg(p0, p1, p2, p3, cd0, b0, a0, a1);
            accum_seg(r0, r1, r2, r3, cd1, b0, a0, a1);
        }
        __syncthreads();
    }

    float4 hv = *(const float4*)(hann + n1);
    float gain = gains[iblk];
    float wsel = (iblk == 0) ? wmix[0] : 1.0f;
    float wn = wmix[iblk + 1];
    size_t base0 = (size_t)b * TT + ((size_t)s0 << 10) + (size_t)n1;
    const float* prevsrc = (iblk == 0) ? x : dout;
    float4 pv0 = *(const float4*)(prevsrc + base0);
    float4 pv1 = *(const float4*)(prevsrc + base0 + 1024);

    float4 yv0, yv1;
    yv0.x = tanh_fast(fmaf(hv.x, p0.y, p0.x) * gain);
    yv0.y = tanh_fast(fmaf(hv.y, p1.y, p1.x) * gain);
    yv0.z = tanh_fast(fmaf(hv.z, p2.y, p2.x) * gain);
    yv0.w = tanh_fast(fmaf(hv.w, p3.y, p3.x) * gain);
    yv1.x = tanh_fast(fmaf(hv.x, r0.y, r0.x) * gain);
    yv1.y = tanh_fast(fmaf(hv.y, r1.y, r1.x) * gain);
    yv1.z = tanh_fast(fmaf(hv.z, r2.y, r2.x) * gain);
    yv1.w = tanh_fast(fmaf(hv.w, r3.y, r3.x) * gain);

    float4 dv0, dv1;
    dv0.x = fmaf(wsel, pv0.x, wn * yv0.x);
    dv0.y = fmaf(wsel, pv0.y, wn * yv0.y);
    dv0.z = fmaf(wsel, pv0.z, wn * yv0.z);
    dv0.w = fmaf(wsel, pv0.w, wn * yv0.w);
    dv1.x = fmaf(wsel, pv1.x, wn * yv1.x);
    dv1.y = fmaf(wsel, pv1.y, wn * yv1.y);
    dv1.z = fmaf(wsel, pv1.z, wn * yv1.z);
    dv1.w = fmaf(wsel, pv1.w, wn * yv1.w);
    *(float4*)(dout + base0) = dv0;
    *(float4*)(dout + base0 + 1024) = dv1;

    if (do_an) {
        ystage4[tid] = yv0;
        ystage4[256 + tid] = yv1;
        __syncthreads();
        int K2 = counts[iblk + 1];
        if (K2 > 0) {
            int lane = tid & 63, w = tid >> 6;
            const float2* cA2 = cisA + (size_t)(iblk + 1) * kmax * 64;
            const float2* cB2 = cisB + (size_t)(iblk + 1) * kmax * 16;
            const float* ys0 = (const float*)ystage4;
            const float* ys1 = ys0 + 1024;
            float xr[16];
#pragma unroll
            for (int i = 0; i < 16; ++i) xr[i] = ys0[lane + (i << 6)];
            half_dft(xr, K2, cA2, cB2, H2 + (size_t)(b * FRM + s0) * K2, lane, w);
#pragma unroll
            for (int i = 0; i < 16; ++i) xr[i] = ys1[lane + (i << 6)];
            half_dft(xr, K2, cA2, cB2, H2 + (size_t)(b * FRM + s0 + 1) * K2, lane, w);
        }
    }
}

extern "C" void kernel_launch(void* const* d_in, const int* in_sizes, int n_in,
                              void* d_out, int out_size, void* d_ws, size_t ws_size,
                              hipStream_t stream)
{
    const float* x         = (const float*)d_in[0];
    const float* transfers = (const float*)d_in[1];
    const float* gains     = (const float*)d_in[2];
    const float* mixer     = (const float*)d_in[3];
    float* dout = (float*)d_out;

    uint8_t* ws = (uint8_t*)d_ws;
    int*   counts = (int*)ws;                          // 16 B
    int*   bins   = (int*)(ws + 64);                   // 4*1025*4 = 16400 B
    float* tvals  = (float*)(ws + 64 + 16400);         // 16400 B
    float* wmix   = (float*)(ws + 64 + 16400 + 16400); // 20 B
    float* hann   = (float*)(ws + 36864);              // 1024 floats
    const size_t HDR = 65536;

    // per-k bytes: two ping-pong S buffers (2*BAT*FRM*8) + cisA (NB*64*8) + cisB (NB*16*8)
    long long perk = 2LL * BAT * FRM * 8 + (long long)NB * 80 * 8;
    long long km = ((long long)ws_size - (long long)HDR) / perk;
    int kmax = (int)((km < 1) ? 1 : ((km > NC) ? NC : km));
    float2* S0 = (float2*)(ws + HDR);
    float2* S1 = S0 + (size_t)BAT * FRM * kmax;
    float2* cisA = S1 + (size_t)BAT * FRM * kmax;      // NB * kmax * 64 float2
    float2* cisB = cisA + (size_t)NB * kmax * 64;      // NB * kmax * 16 float2

    setup_kernel<<<NB, 1024, 0, stream>>>(transfers, mixer, counts, bins, tvals, wmix, hann, kmax);
    table_kernel<<<NB * 4, 256, 0, stream>>>(counts, bins, cisA, cisB, kmax);
    analysis_kernel<<<BAT * FRM, 256, 0, stream>>>(x, counts, cisA, cisB, S0, 0, kmax);

    float2* cur = S0;
    float2* nxt = S1;
    for (int i = 0; i < NB; ++i) {
        scan_kernel<<<BAT * 32, 256, 0, stream>>>(cur, counts, bins, tvals, i);
        fused_synth_kernel<<<BAT * 128, 256, 0, stream>>>(cur, nxt, cisA, cisB, counts, bins,
                                                          gains, wmix, hann, x, dout, i,
                                                          (i < NB - 1) ? 1 : 0, kmax);
        float2* t = cur; cur = nxt; nxt = t;
    }
}

// Round 8
// 284.904 us; speedup vs baseline: 1.0758x; 1.0333x over previous
//
#include <hip/hip_runtime.h>
#include <math.h>
#include <stdint.h>

#define NB   4
#define NC   1025
#define WSZ  2048
#define STEP 1024
#define FRM  256
#define BAT  32
#define TT   262144
#define KC   32      // bin chunk per rc-build in the synth kernel
#define YPAD 68      // floats per 64-sample ystage chunk (+4 pad: conflict-free strides)

// 1/2048 (exact): phases are integers mod 2048 -> revolutions for v_sin/v_cos
#define RREV (1.0f / 2048.0f)

typedef float f2 __attribute__((ext_vector_type(2)));

__device__ __forceinline__ float tanh_fast(float z) {
    float e = __expf(2.0f * z);
    return 1.0f - 2.0f / (e + 1.0f);   // exact tanh identity; inf/0 saturate to +/-1
}

// hardware cis: idx taken mod 2048, argument in revolutions (exact, no range reduction)
__device__ __forceinline__ void cis_rev(int idx, float* c, float* s) {
    float rev = (float)(idx & 2047) * RREV;
    *c = __builtin_amdgcn_cosf(rev);
    *s = __builtin_amdgcn_sinf(rev);
}

// ---------------- setup: compact nonzero bins per block + softmax(mixer) + hann table ----------------
__global__ __launch_bounds__(1024) void setup_kernel(
    const float* __restrict__ transfers, const float* __restrict__ mixer,
    int* __restrict__ counts, int* __restrict__ bins, float* __restrict__ tvals,
    float* __restrict__ wmix, float* __restrict__ hann, int kmax)
{
    int i = blockIdx.x, tid = threadIdx.x;
    __shared__ int wcnt[16], woff[16];
    if (i == 0) {                                   // hann[n] = 0.5 - 0.5 cos(2pi n/2048)
        float cc, ss; cis_rev(tid, &cc, &ss);
        hann[tid] = 0.5f - 0.5f * cc;
    }
    float tv = transfers[i * NC + tid];
    bool nz = (tv != 0.0f);
    unsigned long long mask = __ballot(nz);
    int lane = tid & 63, w = tid >> 6;
    int within = __popcll(mask & ((1ULL << lane) - 1ULL));
    if (lane == 0) wcnt[w] = __popcll(mask);
    __syncthreads();
    if (tid == 0) {
        int acc = 0;
        for (int q = 0; q < 16; ++q) { woff[q] = acc; acc += wcnt[q]; }
        float tvL = transfers[i * NC + 1024];       // tail bin k=1024
        if (tvL != 0.0f && acc < kmax) { bins[i * NC + acc] = 1024; tvals[i * NC + acc] = tvL; acc++; }
        counts[i] = (acc < kmax) ? acc : kmax;
        if (i == 0) {                               // softmax of mixer[5]
            float m = mixer[0];
            for (int q = 1; q < 5; ++q) m = fmaxf(m, mixer[q]);
            float e[5], s = 0.f;
            for (int q = 0; q < 5; ++q) { e[q] = __expf(mixer[q] - m); s += e[q]; }
            for (int q = 0; q < 5; ++q) wmix[q] = e[q] / s;
        }
    }
    __syncthreads();
    if (nz) {
        int pos = woff[w] + within;
        if (pos < kmax) { bins[i * NC + pos] = tid; tvals[i * NC + pos] = tv; }
    }
}

// ---------------- factored twiddle tables (tiny, L1-resident) ----------------
// cisA[i][j][m] = cis(2pi k_j m /2048), m in [0,64);  cisB[i][j][q] = cis(2pi k_j 64 q/2048), q in [0,16)
__global__ __launch_bounds__(256) void table_kernel(
    const int* __restrict__ counts, const int* __restrict__ bins,
    float2* __restrict__ cisA, float2* __restrict__ cisB, int kmax)
{
    int i = blockIdx.x >> 2, c = blockIdx.x & 3;
    int K = counts[i];
    int tid = threadIdx.x;
    for (int j = c; j < K; j += 4) {
        int k = bins[i * NC + j];
        if (tid < 64) {
            float cc, ss; cis_rev(k * tid, &cc, &ss);
            cisA[((size_t)i * kmax + j) * 64 + tid] = make_float2(cc, ss);
        } else if (tid < 80) {
            int q = tid - 64;
            float cc, ss; cis_rev(k * 64 * q, &cc, &ss);
            cisB[((size_t)i * kmax + j) * 16 + q] = make_float2(cc, ss);
        }
    }
}

// shared half-frame DFT (standalone analysis of x only): xr[16] per lane (n = lane + 64*i),
// bins j = w, w+4, ... < K; W = conj(cisB[j][1]); final rotate by conj(cisA[j][lane]).
__device__ __forceinline__ void half_dft(
    const float xr[16], int K, const float2* __restrict__ cA,
    const float2* __restrict__ cB, float2* __restrict__ Hout, int lane, int w)
{
    for (int j = w; j < K; j += 8) {
        int j2 = j + 4;
        bool two = (j2 < K);
        float2 bA = cB[(size_t)j * 16 + 1];
        float2 bB = two ? cB[(size_t)j2 * 16 + 1] : bA;
        float2 wAl = cA[(size_t)j * 64 + lane];
        float2 wBl = two ? cA[(size_t)j2 * 64 + lane] : wAl;
        f2 Wr, Wi, nWi;
        Wr.x = bA.x; Wr.y = bB.x;
        Wi.x = -bA.y; Wi.y = -bB.y;              // W = conj(cis(64k))
        nWi = -Wi;
        f2 hr = 0.f, hi = 0.f;                   // packed Horner: lane0=binA, lane1=binB
#pragma unroll
        for (int i = 15; i >= 0; --i) {
            f2 xx; xx.x = xr[i]; xx.y = xr[i];
            f2 tmp = nWi * hi + xx;              // pk_fma
            f2 nr = Wr * hr + tmp;               // pk_fma
            hi = Wi * hr + Wr * hi;
            hr = nr;
        }
        f2 wlc, wls;
        wlc.x = wAl.x; wlc.y = wBl.x;
        wls.x = wAl.y; wls.y = wBl.y;
        f2 re = hr * wlc + hi * wls;
        f2 im = hi * wlc - hr * wls;
        float reA = re.x, imA = im.x, reB = re.y, imB = im.y;
#pragma unroll
        for (int m = 32; m >= 1; m >>= 1) {
            reA += __shfl_xor(reA, m, 64);
            imA += __shfl_xor(imA, m, 64);
            reB += __shfl_xor(reB, m, 64);
            imB += __shfl_xor(imB, m, 64);
        }
        if (lane == 0) {
            Hout[j] = make_float2(reA, imA);
            if (two) Hout[j2] = make_float2(reB, imB);
        }
    }
}

// ---------------- analysis (block 0 only): sparse DFT of each 1024-sample half-frame ----------------
__global__ __launch_bounds__(256, 8) void analysis_kernel(
    const float* __restrict__ x, const int* __restrict__ counts,
    const float2* __restrict__ cisA, const float2* __restrict__ cisB,
    float2* __restrict__ H, int iblk, int kmax)
{
    int wg = blockIdx.x;
    int b = wg >> 8, h = wg & 255;
    int tid = threadIdx.x;
    int lane = tid & 63, w = tid >> 6;
    int K = counts[iblk];
    const float* xb = x + (size_t)b * TT + (size_t)h * STEP;
    float xr[16];
#pragma unroll
    for (int i = 0; i < 16; ++i) xr[i] = xb[lane + (i << 6)];
    const float2* cA = cisA + (size_t)iblk * kmax * 64;
    const float2* cB = cisB + (size_t)iblk * kmax * 16;
    float2* Hout = H + (size_t)(b * FRM + h) * K;
    half_dft(xr, K, cA, cB, Hout, lane, w);
}

// ---------------- scan: S_f = H_f + (-1)^k H_{f+1};  O_f = (S_f + O_{f-1}) * t ----------------
__global__ __launch_bounds__(256) void scan_kernel(
    float2* __restrict__ S, const int* __restrict__ counts,
    const int* __restrict__ bins, const float* __restrict__ tvals, int iblk)
{
    int K = counts[iblk];
    int wg = blockIdx.x;
    int b = wg & (BAT - 1), j0 = wg >> 5;
    int f = threadIdx.x;
    __shared__ f2 sha[FRM];
    __shared__ float shg[FRM];
    for (int j = j0; j < K; j += 32) {
        float t = tvals[iblk * NC + j];
        int k = bins[iblk * NC + j];
        float2* Sb = S + (size_t)b * FRM * K + j;
        float2 h1 = Sb[(size_t)f * K];
        float2 h2 = (f < FRM - 1) ? Sb[(size_t)(f + 1) * K] : make_float2(0.f, 0.f);
        float sgn = (k & 1) ? -t : t;
        f2 a;
        a.x = fmaf(sgn, h2.x, h1.x * t);
        a.y = fmaf(sgn, h2.y, h1.y * t);
        float g = t;
#pragma unroll
        for (int d = 1; d < FRM; d <<= 1) {
            sha[f] = a; shg[f] = g;
            __syncthreads();
            if (f >= d) {
                f2 gg; gg.x = g; gg.y = g;
                a = gg * sha[f - d] + a;         // pk_fma
                g *= shg[f - d];
            }
            __syncthreads();
        }
        Sb[(size_t)f * K] = make_float2(a.x, a.y);
        __syncthreads();
    }
}

// accumulate 4 samples for one (seg, bin): acc_i += up*c_i + vp*s_i
__device__ __forceinline__ void acc4(
    f2& q0, f2& q1, f2& q2, f2& q3, float4 e, float4 a0, float4 a1)
{
    f2 up; up.x = e.x; up.y = e.y;
    f2 vp; vp.x = e.z; vp.y = e.w;
    q0 = up * a0.x + q0; q0 = vp * a0.y + q0;
    q1 = up * a0.z + q1; q1 = vp * a0.w + q1;
    q2 = up * a1.x + q2; q2 = vp * a1.y + q2;
    q3 = up * a1.z + q3; q3 = vp * a1.w + q3;
}

// ---------------- fused synthesis (2 segments/wg) + next-block analysis ----------------
// Synthesis: rotated coefs rc[seg][j][q] = coef*cis(64kq) precomputed in LDS (kills the
// per-thread rotate); inner loop = 16 pk + 2 global(L1) + 2 LDS-broadcast reads per bin.
// Analysis: transposed mapping, thread = (bin j, 64-sample chunk c), both segs packed in
// f2 Horner; one LDS partial per thread, 16-thread final sum -- zero shuffle reductions.
__global__ __launch_bounds__(256, 8) void fused_synth_kernel(
    const float2* __restrict__ S, float2* __restrict__ H2,
    const float2* __restrict__ cisA, const float2* __restrict__ cisB,
    const int* __restrict__ counts, const int* __restrict__ bins,
    const float* __restrict__ gains, const float* __restrict__ wmix,
    const float* __restrict__ hann, const float* __restrict__ x,
    float* __restrict__ dout, int iblk, int do_an, int kmax)
{
    // union: rc (synth phase) overlaps ystage+part (analysis phase); barrier-separated
    __shared__ float4 smem[1024];                 // 16 KB
    float4* rc = smem;                            // [2][KC][16] float4
    float*  ystage = (float*)smem;                // [2][16][YPAD] floats = 8704 B
    float4* part = smem + 544;                    // [16][16] float4 = 4 KB

    int wg = blockIdx.x;
    int b = wg >> 7, s0 = (wg & 127) << 1;
    int tid = threadIdx.x;
    int n1 = tid << 2;
    int q = tid >> 4;            // [0,16)
    int m = (tid & 15) << 2;     // [0,64) step 4

    int K = counts[iblk];
    const int* bl = bins + iblk * NC;
    const float2* Ob = S + (size_t)b * FRM * K;
    const float2* cA0 = cisA + (size_t)iblk * kmax * 64;
    const float2* cB0 = cisB + (size_t)iblk * kmax * 16;

    // early prefetch of epilogue operands (consumed after the loop)
    size_t base0 = (size_t)b * TT + ((size_t)s0 << 10) + (size_t)n1;
    const float* prevsrc = (iblk == 0) ? x : dout;
    float4 pv0 = *(const float4*)(prevsrc + base0);
    float4 pv1 = *(const float4*)(prevsrc + base0 + 1024);
    float4 hv = *(const float4*)(hann + n1);
    float gain = gains[iblk];
    float wsel = (iblk == 0) ? wmix[0] : 1.0f;
    float wn = wmix[iblk + 1];

    f2 p0 = 0.f, p1 = 0.f, p2 = 0.f, p3 = 0.f;   // seg s0   (A,B) packed
    f2 r0 = 0.f, r1 = 0.f, r2 = 0.f, r3 = 0.f;   // seg s0+1

    for (int c0 = 0; c0 < K; c0 += KC) {
        int cs = (K - c0 < KC) ? (K - c0) : KC;
        {   // build rc: 4 threads per (seg,j), each does 4 q-entries
            int flat = tid >> 2;                  // 0..63 = seg*KC + j
            int seg = flat >> 5;
            int j = flat & 31;
            int jj = c0 + ((j < cs) ? j : (cs - 1));
            int q0 = (tid & 3) << 2;
            int k = bl[jj];
            float g = ((k == 0) || (k == 1024)) ? (1.0f / 2048.0f) : (2.0f / 2048.0f);
            float sg = (k & 1) ? -g : g;
            int fc = s0 + seg;
            float2 o1 = Ob[(size_t)fc * K + jj];
            float2 om = (fc > 0) ? Ob[(size_t)(fc - 1) * K + jj] : make_float2(0.f, 0.f);
            float c2r = om.x * sg, c2i = om.y * sg;
            f2 u; u.x = c2r;  u.y = o1.x * g - c2r;
            f2 v; v.x = -c2i; v.y = -(o1.y * g - c2i);
            const float2* bqp = cB0 + (size_t)jj * 16 + q0;
#pragma unroll
            for (int e = 0; e < 4; ++e) {
                float2 bq = bqp[e];
                f2 up = u * bq.x + v * bq.y;
                f2 vp = v * bq.x - u * bq.y;
                rc[(flat << 4) + q0 + e] = make_float4(up.x, up.y, vp.x, vp.y);
            }
        }
        __syncthreads();
        const float2* cAj = cA0 + ((size_t)c0 << 6) + m;
        const float4* rcq = rc + q;
        int jj = 0;
        for (; jj + 2 <= cs; jj += 2) {
            float4 a00 = *(const float4*)(cAj);
            float4 a01 = *(const float4*)(cAj + 2);
            float4 a10 = *(const float4*)(cAj + 64);
            float4 a11 = *(const float4*)(cAj + 66);
            cAj += 128;
            float4 e00 = rcq[jj << 4];
            float4 e01 = rcq[(KC + jj) << 4];
            float4 e10 = rcq[(jj + 1) << 4];
            float4 e11 = rcq[(KC + jj + 1) << 4];
            acc4(p0, p1, p2, p3, e00, a00, a01);
            acc4(r0, r1, r2, r3, e01, a00, a01);
            acc4(p0, p1, p2, p3, e10, a10, a11);
            acc4(r0, r1, r2, r3, e11, a10, a11);
        }
        if (jj < cs) {
            float4 a0 = *(const float4*)(cAj);
            float4 a1 = *(const float4*)(cAj + 2);
            float4 e0 = rcq[jj << 4];
            float4 e1 = rcq[(KC + jj) << 4];
            acc4(p0, p1, p2, p3, e0, a0, a1);
            acc4(r0, r1, r2, r3, e1, a0, a1);
        }
        __syncthreads();
    }

    float4 yv0, yv1;
    yv0.x = tanh_fast(fmaf(hv.x, p0.y, p0.x) * gain);
    yv0.y = tanh_fast(fmaf(hv.y, p1.y, p1.x) * gain);
    yv0.z = tanh_fast(fmaf(hv.z, p2.y, p2.x) * gain);
    yv0.w = tanh_fast(fmaf(hv.w, p3.y, p3.x) * gain);
    yv1.x = tanh_fast(fmaf(hv.x, r0.y, r0.x) * gain);
    yv1.y = tanh_fast(fmaf(hv.y, r1.y, r1.x) * gain);
    yv1.z = tanh_fast(fmaf(hv.z, r2.y, r2.x) * gain);
    yv1.w = tanh_fast(fmaf(hv.w, r3.y, r3.x) * gain);

    float4 dv0, dv1;
    dv0.x = fmaf(wsel, pv0.x, wn * yv0.x);
    dv0.y = fmaf(wsel, pv0.y, wn * yv0.y);
    dv0.z = fmaf(wsel, pv0.z, wn * yv0.z);
    dv0.w = fmaf(wsel, pv0.w, wn * yv0.w);
    dv1.x = fmaf(wsel, pv1.x, wn * yv1.x);
    dv1.y = fmaf(wsel, pv1.y, wn * yv1.y);
    dv1.z = fmaf(wsel, pv1.z, wn * yv1.z);
    dv1.w = fmaf(wsel, pv1.w, wn * yv1.w);
    *(float4*)(dout + base0) = dv0;
    *(float4*)(dout + base0 + 1024) = dv1;

    if (do_an) {
        // stage y into padded LDS: [seg][chunk c][YPAD]
        int cw = n1 >> 6, off = n1 & 63;
        *(float4*)(ystage + cw * YPAD + off) = yv0;
        *(float4*)(ystage + 16 * YPAD + cw * YPAD + off) = yv1;
        __syncthreads();
        int K2 = counts[iblk + 1];
        if (K2 > 0) {
            const float2* cA2 = cisA + (size_t)(iblk + 1) * kmax * 64;
            const float2* cB2 = cisB + (size_t)(iblk + 1) * kmax * 16;
            int jloc = tid & 15, c = tid >> 4;
            const float4* yp0 = (const float4*)(ystage + c * YPAD);
            const float4* yp1 = (const float4*)(ystage + 16 * YPAD + c * YPAD);
            for (int jb = 0; jb < K2; jb += 16) {
                int j = jb + jloc;
                int js = (j < K2) ? j : (K2 - 1);
                float2 w1 = cA2[(size_t)js * 64 + 1];   // cis(k)
                float Wr = w1.x, Wi = -w1.y, nWi = w1.y;
                f2 hr = 0.f, hi = 0.f;                  // packed over (seg0, seg1)
#pragma unroll
                for (int i4 = 15; i4 >= 0; --i4) {
                    float4 ya = yp0[i4];
                    float4 yb = yp1[i4];
                    { f2 yy; yy.x = ya.w; yy.y = yb.w;
                      f2 t = hi * nWi + yy; f2 nr = hr * Wr + t; hi = hr * Wi + hi * Wr; hr = nr; }
                    { f2 yy; yy.x = ya.z; yy.y = yb.z;
                      f2 t = hi * nWi + yy; f2 nr = hr * Wr + t; hi = hr * Wi + hi * Wr; hr = nr; }
                    { f2 yy; yy.x = ya.y; yy.y = yb.y;
                      f2 t = hi * nWi + yy; f2 nr = hr * Wr + t; hi = hr * Wi + hi * Wr; hr = nr; }
                    { f2 yy; yy.x = ya.x; yy.y = yb.x;
                      f2 t = hi * nWi + yy; f2 nr = hr * Wr + t; hi = hr * Wi + hi * Wr; hr = nr; }
                }
                float2 bq = cB2[(size_t)js * 16 + c];   // rotate by cis(-64kc)
                f2 re = hr * bq.x + hi * bq.y;
                f2 im = hi * bq.x - hr * bq.y;
                part[c * 16 + jloc] = make_float4(re.x, im.x, re.y, im.y);
                __syncthreads();
                if (tid < 16) {
                    int j2 = jb + tid;
                    if (j2 < K2) {
                        float4 acc = part[tid];
                        for (int cc = 1; cc < 16; ++cc) {
                            float4 pp = part[cc * 16 + tid];
                            acc.x += pp.x; acc.y += pp.y; acc.z += pp.z; acc.w += pp.w;
                        }
                        H2[(size_t)(b * FRM + s0) * K2 + j2] = make_float2(acc.x, acc.y);
                        H2[(size_t)(b * FRM + s0 + 1) * K2 + j2] = make_float2(acc.z, acc.w);
                    }
                }
                __syncthreads();
            }
        }
    }
}

extern "C" void kernel_launch(void* const* d_in, const int* in_sizes, int n_in,
                              void* d_out, int out_size, void* d_ws, size_t ws_size,
                              hipStream_t stream)
{
    const float* x         = (const float*)d_in[0];
    const float* transfers = (const float*)d_in[1];
    const float* gains     = (const float*)d_in[2];
    const float* mixer     = (const float*)d_in[3];
    float* dout = (float*)d_out;

    uint8_t* ws = (uint8_t*)d_ws;
    int*   counts = (int*)ws;                          // 16 B
    int*   bins   = (int*)(ws + 64);                   // 4*1025*4 = 16400 B
    float* tvals  = (float*)(ws + 64 + 16400);         // 16400 B
    float* wmix   = (float*)(ws + 64 + 16400 + 16400); // 20 B
    float* hann   = (float*)(ws + 36864);              // 1024 floats
    const size_t HDR = 65536;

    // per-k bytes: two ping-pong S buffers (2*BAT*FRM*8) + cisA (NB*64*8) + cisB (NB*16*8)
    long long perk = 2LL * BAT * FRM * 8 + (long long)NB * 80 * 8;
    long long km = ((long long)ws_size - (long long)HDR) / perk;
    int kmax = (int)((km < 1) ? 1 : ((km > NC) ? NC : km));
    float2* S0 = (float2*)(ws + HDR);
    float2* S1 = S0 + (size_t)BAT * FRM * kmax;
    float2* cisA = S1 + (size_t)BAT * FRM * kmax;      // NB * kmax * 64 float2
    float2* cisB = cisA + (size_t)NB * kmax * 64;      // NB * kmax * 16 float2

    setup_kernel<<<NB, 1024, 0, stream>>>(transfers, mixer, counts, bins, tvals, wmix, hann, kmax);
    table_kernel<<<NB * 4, 256, 0, stream>>>(counts, bins, cisA, cisB, kmax);
    analysis_kernel<<<BAT * FRM, 256, 0, stream>>>(x, counts, cisA, cisB, S0, 0, kmax);

    float2* cur = S0;
    float2* nxt = S1;
    for (int i = 0; i < NB; ++i) {
        scan_kernel<<<BAT * 32, 256, 0, stream>>>(cur, counts, bins, tvals, i);
        fused_synth_kernel<<<BAT * 128, 256, 0, stream>>>(cur, nxt, cisA, cisB, counts, bins,
                                                          gains, wmix, hann, x, dout, i,
                                                          (i < NB - 1) ? 1 : 0, kmax);
        float2* t = cur; cur = nxt; nxt = t;
    }
}